// Round 2
// baseline (226.801 us; speedup 1.0000x reference)
//
#include <hip/hip_runtime.h>
#include <stdint.h>

// Problem constants (fixed by the reference).
#define VOCAB_P1 100001
#define EMB_DIM  128
#define BATCH    256
#define NNZ_Q    2048
#define NNZ_D    262144

#define NPAD 112        // hidden dim 100 padded to 7 MFMA tiles of 16
#define ROWP 136        // w1t LDS row stride in shorts (128 + 8 pad)
#define NGRP 6251       // ceil(100001 / 16) row-groups
#define BINBLK 512      // bin-role blocks (2 entries/thread)

#define NBKT 3126       // ceil(100001 / 32) row buckets
#define BCAP 192        // bucket capacity (mean 84, P(overflow) ~ 1e-48)
#define CSC  64         // colsum copies (contention spread)

// Workspace layout (byte offsets, all 16B aligned). Total ~5.31 MB.
#define WS_BCNT  0        // int  [3126]           (zeroed by memset)
#define WS_CS    12544    // f32  [64][256]        (zeroed by memset)
#define WS_RSUM  78080    // f32  [100001]
#define WS_W1BF  478096   // bf16 [NPAD*ROWP] pre-transposed/padded W1
#define WS_BIN   508560   // int2 [3126*192]

typedef __attribute__((ext_vector_type(8))) short  short8;
typedef __attribute__((ext_vector_type(4))) float  float4v;

__device__ __forceinline__ unsigned short f2bf(float f) {
    union { float f; unsigned u; } v; v.f = f;
    unsigned u = v.u;
    u += 0x7fffu + ((u >> 16) & 1u);     // RNE float -> bf16
    return (unsigned short)(u >> 16);
}

__device__ __forceinline__ short8 cvt8(float4 a, float4 b) {
    short8 r;
    r[0] = (short)f2bf(a.x); r[1] = (short)f2bf(a.y);
    r[2] = (short)f2bf(a.z); r[3] = (short)f2bf(a.w);
    r[4] = (short)f2bf(b.x); r[5] = (short)f2bf(b.y);
    r[6] = (short)f2bf(b.z); r[7] = (short)f2bf(b.w);
    return r;
}

// K1: blocks [0,BINBLK): bin d-entries into 32-row buckets (bcnt pre-zeroed
// by memset node). Block BINBLK: build the bf16 transposed/padded W1 image
// once (compose blocks then stage it with straight int4 copies).
__global__ __launch_bounds__(256) void bin_w1_kernel(
    const int* __restrict__ d_rows, const int* __restrict__ d_cols,
    const float* __restrict__ d_freqs,
    int* __restrict__ bcnt, int2* __restrict__ binbuf,
    int* __restrict__ w1bfi, const float* __restrict__ W1)
{
    const int tid = threadIdx.x;

    if (blockIdx.x == BINBLK) {
        // w1bf: 15232 shorts = 7616 ints, value-filled (pads = 0)
        for (int i = tid; i < (NPAD * ROWP) / 2; i += 256) {
            int p0 = 2 * i, p1 = 2 * i + 1;
            int j0 = p0 / ROWP, k0 = p0 - j0 * ROWP;
            int j1 = p1 / ROWP, k1 = p1 - j1 * ROWP;
            unsigned lo = (j0 < 100 && k0 < 128) ? f2bf(W1[k0 * 100 + j0]) : 0u;
            unsigned hi = (j1 < 100 && k1 < 128) ? f2bf(W1[k1 * 100 + j1]) : 0u;
            w1bfi[i] = (int)(lo | (hi << 16));
        }
        return;
    }

    int g = blockIdx.x * 256 + tid;   // int2 index, 131072 total
    int2   r2 = ((const int2*)d_rows)[g];
    int2   c2 = ((const int2*)d_cols)[g];
    float2 f2 = ((const float2*)d_freqs)[g];
    int bk0 = r2.x >> 5, bk1 = r2.y >> 5;
    int i0 = atomicAdd(&bcnt[bk0], 1);
    int i1 = atomicAdd(&bcnt[bk1], 1);
    if (i0 < BCAP)
        binbuf[bk0 * BCAP + i0] = make_int2(((r2.x & 31) << 8) | c2.x,
                                            __float_as_int(f2.x));
    if (i1 < BCAP)
        binbuf[bk1 * BCAP + i1] = make_int2(((r2.y & 31) << 8) | c2.y,
                                            __float_as_int(f2.y));
}

// K2: fused compose. Per block (32 rows of dmat):
//   phase A: waves 0-1 compute tdv for the block's 32 rows via MFMA
//            (W1 staged in LDS; layout m89/m91-verified). Waves 2-3 idle
//            at the barrier with their bin entry loads already in flight.
//   phase B: reuse the SAME LDS (union) as a 32x256 tile: zero, apply
//            binned entries via LDS atomics, stream out ONCE (float4),
//            produce rowsum + per-block colsum partials.
// No global tdvtab, no global zero pass, no global atomics to dmat.
__global__ __launch_bounds__(256) void compose_kernel(
    const int* __restrict__ bcnt, const int2* __restrict__ binbuf,
    const float* __restrict__ emb, const float* __restrict__ b1,
    const float* __restrict__ W2, const float* __restrict__ b2,
    const short* __restrict__ w1bf,
    float* __restrict__ dmat, float* __restrict__ rowsum,
    float* __restrict__ colsum2)
{
    __shared__ __align__(16) char uu[32 * 256 * 4];  // 32KB union
    short* w1t  = (short*)uu;                        // phase A: [NPAD*ROWP]
    float* tile = (float*)uu;                        // phase B: [32][256]
    __shared__ float b1s[NPAD];
    __shared__ float w2s[NPAD];
    __shared__ float tdv32[32];

    const int tid = threadIdx.x;
    const int blk = blockIdx.x;
    const int row0 = blk * 32;

    // stage pre-converted W1: 1904 int4, coalesced, conflict-free
    {
        const int4* src = (const int4*)w1bf;
        int4* dst = (int4*)w1t;
        #pragma unroll
        for (int k = 0; k < 8; ++k) {
            int idx = tid + k * 256;
            if (idx < (NPAD * ROWP * 2) / 16) dst[idx] = src[idx];
        }
    }
    if (tid < NPAD) {
        b1s[tid] = (tid < 100) ? b1[tid] : 0.f;
        w2s[tid] = (tid < 100) ? W2[tid] : 0.f;
    }

    // bin entry prefetch (global loads in flight across phase A)
    int cnt = bcnt[blk]; if (cnt > BCAP) cnt = BCAP;
    int bi = (tid < cnt) ? tid : 0;
    int2 e = binbuf[blk * BCAP + bi];

    __syncthreads();

    // ---- phase A: MLP for this block's 32 rows (waves 0,1) ----
    {
        const int lane = tid & 63;
        const int w    = tid >> 6;
        const int col  = lane & 15;
        const int quad = lane >> 4;
        const int grp  = blk * 2 + w;               // 16-row group per wave

        if (w < 2 && grp < NGRP) {
            const float b2v = b2[0];
            int r  = grp * 16 + col;
            int rr = (r <= VOCAB_P1 - 1) ? r : (VOCAB_P1 - 1);
            const float* rp = emb + (size_t)rr * EMB_DIM + quad * 8;
            // A layout: A[m=lane&15][k=quad*8+j]  (m89/m91-verified)
            float4 u0 = *(const float4*)(rp);
            float4 u1 = *(const float4*)(rp + 4);
            float4 u2 = *(const float4*)(rp + 32);
            float4 u3 = *(const float4*)(rp + 36);
            float4 u4 = *(const float4*)(rp + 64);
            float4 u5 = *(const float4*)(rp + 68);
            float4 u6 = *(const float4*)(rp + 96);
            float4 u7 = *(const float4*)(rp + 100);
            short8 a0 = cvt8(u0, u1), a1 = cvt8(u2, u3);
            short8 a2 = cvt8(u4, u5), a3 = cvt8(u6, u7);

            float s0 = 0.f, s1 = 0.f, s2 = 0.f, s3 = 0.f;
            for (int jt = 0; jt < 7; ++jt) {
                const short* bp = &w1t[(jt * 16 + col) * ROWP + quad * 8];
                short8 bv0 = *(const short8*)(bp);
                short8 bv1 = *(const short8*)(bp + 32);
                short8 bv2 = *(const short8*)(bp + 64);
                short8 bv3 = *(const short8*)(bp + 96);

                float4v acc = {0.f, 0.f, 0.f, 0.f};
                acc = __builtin_amdgcn_mfma_f32_16x16x32_bf16(a0, bv0, acc, 0, 0, 0);
                acc = __builtin_amdgcn_mfma_f32_16x16x32_bf16(a1, bv1, acc, 0, 0, 0);
                acc = __builtin_amdgcn_mfma_f32_16x16x32_bf16(a2, bv2, acc, 0, 0, 0);
                acc = __builtin_amdgcn_mfma_f32_16x16x32_bf16(a3, bv3, acc, 0, 0, 0);

                // D layout: row = quad*4 + reg, col(j) = lane&15
                float b1v = b1s[jt * 16 + col];
                float w2v = w2s[jt * 16 + col];
                float h;
                h = acc[0] + b1v; h = h > 0.f ? h : 0.f; s0 += h * w2v;
                h = acc[1] + b1v; h = h > 0.f ? h : 0.f; s1 += h * w2v;
                h = acc[2] + b1v; h = h > 0.f ? h : 0.f; s2 += h * w2v;
                h = acc[3] + b1v; h = h > 0.f ? h : 0.f; s3 += h * w2v;
            }
            for (int m = 1; m < 16; m <<= 1) {
                s0 += __shfl_xor(s0, m, 64);
                s1 += __shfl_xor(s1, m, 64);
                s2 += __shfl_xor(s2, m, 64);
                s3 += __shfl_xor(s3, m, 64);
            }
            if (col < 4) {
                float sv = (col == 0) ? s0 : (col == 1) ? s1 : (col == 2) ? s2 : s3;
                int row = grp * 16 + quad * 4 + col;
                if (row < VOCAB_P1) {
                    float tdv = sv + b2v;
                    tdv32[w * 16 + quad * 4 + col] = tdv > 0.f ? tdv : 0.f;
                }
            }
        }
    }
    __syncthreads();   // w1t dead from here; tdv32 ready

    // ---- phase B: build the 32x256 tile ----
    {
        const float4 z = {0.f, 0.f, 0.f, 0.f};
        float4* t4 = (float4*)tile;
        #pragma unroll
        for (int k = 0; k < 8; ++k) t4[tid + k * 256] = z;
    }
    __syncthreads();

    if (tid < cnt) {
        int rl = e.x >> 8, c = e.x & 255;
        float v = __int_as_float(e.y) * tdv32[rl];
        atomicAdd(&tile[rl * 256 + c], v);
    }
    __syncthreads();

    int vrows = VOCAB_P1 - row0; if (vrows > 32) vrows = 32;

    // streaming write (coalesced float4) — dmat written exactly once
    {
        float4* out4 = (float4*)(dmat + (size_t)row0 * BATCH);
        float4* t4 = (float4*)tile;
        const int lim = vrows * 64;
        #pragma unroll
        for (int k = 0; k < 8; ++k) {
            int idx = tid + k * 256;
            if (idx < lim) out4[idx] = t4[idx];
        }
    }

    // rowsum: 8 threads per row, skewed LDS reads (2-way = free)
    {
        int rl = tid >> 3, seg = tid & 7;
        float s = 0.f;
        #pragma unroll
        for (int j = 0; j < 32; ++j)
            s += tile[rl * 256 + seg * 32 + ((j + tid) & 31)];
        s += __shfl_xor(s, 1, 64);
        s += __shfl_xor(s, 2, 64);
        s += __shfl_xor(s, 4, 64);
        if (seg == 0 && rl < vrows) rowsum[row0 + rl] = s;
    }

    // colsum partial: thread t owns column t (consecutive banks)
    {
        float cs = 0.f;
        #pragma unroll
        for (int r = 0; r < 32; ++r) cs += tile[r * 256 + tid];
        atomicAdd(&colsum2[(blk & (CSC - 1)) * BATCH + tid], cs);
    }
}

// K3: rel. One thread per q-entry: 1 random 4B dmat load + rowsum/colsum
// table lookups. colsum copies reduced once per block into LDS.
__global__ __launch_bounds__(256) void relv2_kernel(
    const int* __restrict__ q_rows, const int* __restrict__ q_cols,
    const float* __restrict__ q_vals, const float* __restrict__ dmat,
    const float* __restrict__ rowsum, const float* __restrict__ colsum2,
    const float* __restrict__ mu_p, float* __restrict__ rel)
{
    __shared__ float csT[BATCH];
    __shared__ float tot4[4];
    const int tid = threadIdx.x;

    float s = 0.f;
    #pragma unroll 8
    for (int k = 0; k < CSC; ++k) s += colsum2[k * BATCH + tid];
    csT[tid] = s;
    float p = s;
    for (int m = 1; m < 64; m <<= 1) p += __shfl_xor(p, m, 64);
    if ((tid & 63) == 0) tot4[tid >> 6] = p;
    __syncthreads();
    float total = tot4[0] + tot4[1] + tot4[2] + tot4[3];

    int e = blockIdx.x * 256 + tid;
    int v = q_rows[e], b = q_cols[e];
    float qv = q_vals[e];
    float mu = mu_p[0];
    float dval = dmat[(size_t)v * BATCH + b];
    float cf   = rowsum[v] / total;
    float dir  = log1pf(dval / (1.f + mu * cf)) + logf(mu / (csT[b] + mu));
    atomicAdd(&rel[b], qv * dir);
}

extern "C" void kernel_launch(void* const* d_in, const int* in_sizes, int n_in,
                              void* d_out, int out_size, void* d_ws, size_t ws_size,
                              hipStream_t stream)
{
    const int*   q_rows  = (const int*)d_in[0];
    const int*   q_cols  = (const int*)d_in[1];
    const float* q_vals  = (const float*)d_in[2];
    const int*   d_rows  = (const int*)d_in[3];
    const int*   d_cols  = (const int*)d_in[4];
    const float* d_freqs = (const float*)d_in[5];
    const float* emb     = (const float*)d_in[6];
    const float* W1      = (const float*)d_in[7];
    const float* b1      = (const float*)d_in[8];
    const float* W2      = (const float*)d_in[9];
    const float* b2      = (const float*)d_in[10];
    const float* mu      = (const float*)d_in[11];

    float* rel  = (float*)d_out;            // output 0: rel [256]
    float* dmat = rel + BATCH;              // output 1: d [100001, 256]

    char*  ws      = (char*)d_ws;
    int*   bcnt    = (int*)(ws + WS_BCNT);
    float* colsum2 = (float*)(ws + WS_CS);
    float* rowsum  = (float*)(ws + WS_RSUM);
    short* w1bf    = (short*)(ws + WS_W1BF);
    int2*  binbuf  = (int2*)(ws + WS_BIN);

    // zero bcnt + colsum copies + rel (memset nodes are graph-capture-legal)
    hipMemsetAsync(ws, 0, WS_RSUM, stream);
    hipMemsetAsync(rel, 0, BATCH * sizeof(float), stream);

    bin_w1_kernel<<<BINBLK + 1, 256, 0, stream>>>(
        d_rows, d_cols, d_freqs, bcnt, binbuf, (int*)w1bf, W1);
    compose_kernel<<<NBKT, 256, 0, stream>>>(
        bcnt, binbuf, emb, b1, W2, b2, w1bf, dmat, rowsum, colsum2);
    relv2_kernel<<<NNZ_Q / 256, 256, 0, stream>>>(
        q_rows, q_cols, q_vals, dmat, rowsum, colsum2, mu, rel);
}

// Round 4
// 209.933 us; speedup vs baseline: 1.0803x; 1.0803x over previous
//
#include <hip/hip_runtime.h>
#include <stdint.h>

// Problem constants (fixed by the reference).
#define VOCAB_P1 100001
#define EMB_DIM  128
#define BATCH    256
#define NNZ_Q    2048
#define NNZ_D    262144

#define NPAD 112        // hidden dim 100 padded to 7 MFMA tiles of 16
#define ROWP 136        // w1t LDS row stride in shorts (128 + 8 pad)
#define NGRP 6251       // ceil(100001 / 16) row-groups
#define BINBLK 512      // bin-role blocks (2 entries/thread)
#define MBLK 1563       // mlp-role blocks: 1563*4 = 6252 waves = 1 group/wave

#define NBKT 3126       // ceil(100001 / 32) row buckets
#define BCAP 192        // bucket capacity (mean 84, P(overflow) ~ 1e-48)
#define CSC  64         // colsum copies (contention spread)

// Workspace layout (byte offsets, 16B aligned). Total ~5.68 MB (<= 5.71 MB
// proven available in round 1).
#define WS_BCNT  0        // int  [3126]    (zeroed by memset)
#define WS_CS    12544    // f32  [64][256] (zeroed by memset)
#define WS_TDV   78080    // f32  [100001]
#define WS_RSUM  478096   // f32  [100001]
#define WS_BIN   878112   // int2 [3126*192]

typedef __attribute__((ext_vector_type(8))) short  short8;
typedef __attribute__((ext_vector_type(4))) float  float4v;

__device__ __forceinline__ unsigned short f2bf(float f) {
    union { float f; unsigned u; } v; v.f = f;
    unsigned u = v.u;
    u += 0x7fffu + ((u >> 16) & 1u);     // RNE float -> bf16
    return (unsigned short)(u >> 16);
}

__device__ __forceinline__ short8 cvt8(float4 a, float4 b) {
    short8 r;
    r[0] = (short)f2bf(a.x); r[1] = (short)f2bf(a.y);
    r[2] = (short)f2bf(a.z); r[3] = (short)f2bf(a.w);
    r[4] = (short)f2bf(b.x); r[5] = (short)f2bf(b.y);
    r[6] = (short)f2bf(b.z); r[7] = (short)f2bf(b.w);
    return r;
}

// K1 block roles (independent work co-scheduled across CUs, no fusion):
//   [0, BINBLK):           bin d-entries into 32-row buckets
//   BINBLK:                zero rel[256]
//   (BINBLK, BINBLK+MBLK]: MLP tdv table, one 16-row group per wave
__global__ __launch_bounds__(256) void mlp_bin_kernel(
    const int* __restrict__ d_rows, const int* __restrict__ d_cols,
    const float* __restrict__ d_freqs,
    int* __restrict__ bcnt, int2* __restrict__ binbuf,
    const float* __restrict__ emb, const float* __restrict__ W1,
    const float* __restrict__ b1, const float* __restrict__ W2,
    const float* __restrict__ b2, float* __restrict__ tdvtab,
    float* __restrict__ rel)
{
    const int tid = threadIdx.x;

    if (blockIdx.x < BINBLK) {
        // ---- bin role ----
        int g = blockIdx.x * 256 + tid;   // int2 index, 131072 total
        int2   r2 = ((const int2*)d_rows)[g];
        int2   c2 = ((const int2*)d_cols)[g];
        float2 f2 = ((const float2*)d_freqs)[g];
        int bk0 = r2.x >> 5, bk1 = r2.y >> 5;
        int i0 = atomicAdd(&bcnt[bk0], 1);
        int i1 = atomicAdd(&bcnt[bk1], 1);
        if (i0 < BCAP)
            binbuf[bk0 * BCAP + i0] = make_int2(((r2.x & 31) << 8) | c2.x,
                                                __float_as_int(f2.x));
        if (i1 < BCAP)
            binbuf[bk1 * BCAP + i1] = make_int2(((r2.y & 31) << 8) | c2.y,
                                                __float_as_int(f2.y));
        return;
    }
    if (blockIdx.x == BINBLK) {
        rel[tid] = 0.f;
        return;
    }

    // ---- MLP role (R0-proven staging: raw W1 -> bf16 transposed in LDS) ----
    __shared__ __align__(16) short w1t[NPAD * ROWP];   // 30464 B
    __shared__ float b1s[NPAD];
    __shared__ float w2s[NPAD];

    int* w1i = (int*)w1t;
    for (int i = tid; i < NPAD * ROWP / 2; i += 256) w1i[i] = 0;
    __syncthreads();
    for (int f = tid; f < EMB_DIM * 100; f += 256) {
        int k = f / 100, j = f - k * 100;
        w1t[j * ROWP + k] = (short)f2bf(W1[f]);
    }
    if (tid < NPAD) {
        b1s[tid] = (tid < 100) ? b1[tid] : 0.f;
        w2s[tid] = (tid < 100) ? W2[tid] : 0.f;
    }
    __syncthreads();

    const int lane = tid & 63;
    const int w    = tid >> 6;
    const int col  = lane & 15;
    const int quad = lane >> 4;
    const float b2v = b2[0];

    const int grp = (blockIdx.x - (BINBLK + 1)) * 4 + w;  // one group per wave
    if (grp >= NGRP) return;

    int r  = grp * 16 + col;
    int rr = (r <= VOCAB_P1 - 1) ? r : (VOCAB_P1 - 1);
    const float* rp = emb + (size_t)rr * EMB_DIM + quad * 8;
    // A layout: A[m=lane&15][k=quad*8+j]  (m89/m91-verified)
    float4 u0 = *(const float4*)(rp);
    float4 u1 = *(const float4*)(rp + 4);
    float4 u2 = *(const float4*)(rp + 32);
    float4 u3 = *(const float4*)(rp + 36);
    float4 u4 = *(const float4*)(rp + 64);
    float4 u5 = *(const float4*)(rp + 68);
    float4 u6 = *(const float4*)(rp + 96);
    float4 u7 = *(const float4*)(rp + 100);
    short8 a0 = cvt8(u0, u1), a1 = cvt8(u2, u3);
    short8 a2 = cvt8(u4, u5), a3 = cvt8(u6, u7);

    float s0 = 0.f, s1 = 0.f, s2 = 0.f, s3 = 0.f;
    for (int jt = 0; jt < 7; ++jt) {
        const short* bp = &w1t[(jt * 16 + col) * ROWP + quad * 8];
        short8 bv0 = *(const short8*)(bp);
        short8 bv1 = *(const short8*)(bp + 32);
        short8 bv2 = *(const short8*)(bp + 64);
        short8 bv3 = *(const short8*)(bp + 96);

        float4v acc = {0.f, 0.f, 0.f, 0.f};
        acc = __builtin_amdgcn_mfma_f32_16x16x32_bf16(a0, bv0, acc, 0, 0, 0);
        acc = __builtin_amdgcn_mfma_f32_16x16x32_bf16(a1, bv1, acc, 0, 0, 0);
        acc = __builtin_amdgcn_mfma_f32_16x16x32_bf16(a2, bv2, acc, 0, 0, 0);
        acc = __builtin_amdgcn_mfma_f32_16x16x32_bf16(a3, bv3, acc, 0, 0, 0);

        // D layout: row = quad*4 + reg, col(j) = lane&15
        float b1v = b1s[jt * 16 + col];
        float w2v = w2s[jt * 16 + col];
        float h;
        h = acc[0] + b1v; h = h > 0.f ? h : 0.f; s0 += h * w2v;
        h = acc[1] + b1v; h = h > 0.f ? h : 0.f; s1 += h * w2v;
        h = acc[2] + b1v; h = h > 0.f ? h : 0.f; s2 += h * w2v;
        h = acc[3] + b1v; h = h > 0.f ? h : 0.f; s3 += h * w2v;
    }
    for (int m = 1; m < 16; m <<= 1) {
        s0 += __shfl_xor(s0, m, 64);
        s1 += __shfl_xor(s1, m, 64);
        s2 += __shfl_xor(s2, m, 64);
        s3 += __shfl_xor(s3, m, 64);
    }
    if (col < 4) {
        float sv = (col == 0) ? s0 : (col == 1) ? s1 : (col == 2) ? s2 : s3;
        int row = grp * 16 + quad * 4 + col;
        if (row < VOCAB_P1) {
            float tdv = sv + b2v;
            tdvtab[row] = tdv > 0.f ? tdv : 0.f;
        }
    }
}

// K2: compose each 32-row stripe of dmat in LDS. rowsum/colsum are computed
// DIRECTLY from the ~84 entries (LDS atomics into rs[32]/cs[256]) instead of
// scanning the 32KB tile twice -- saves ~64KB of LDS reads per block.
// dmat written exactly once, coalesced float4.
__global__ __launch_bounds__(256) void compose_kernel(
    const int* __restrict__ bcnt, const int2* __restrict__ binbuf,
    const float* __restrict__ tdvtab, float* __restrict__ dmat,
    float* __restrict__ rowsum, float* __restrict__ colsum2)
{
    __shared__ float tile[32 * 256];   // 32 KB
    __shared__ float rs[32];
    __shared__ float cs[BATCH];
    __shared__ float tdvs[32];
    const int tid = threadIdx.x;
    const int blk = blockIdx.x;
    const int row0 = blk * 32;

    const float4 z = {0.f, 0.f, 0.f, 0.f};
    float4* t4 = (float4*)tile;
    #pragma unroll
    for (int k = 0; k < 8; ++k) t4[tid + k * 256] = z;
    if (tid < 32) {
        rs[tid] = 0.f;
        int r = row0 + tid;
        tdvs[tid] = (r < VOCAB_P1) ? tdvtab[r] : 0.f;
    }
    cs[tid] = 0.f;
    int cnt = bcnt[blk]; if (cnt > BCAP) cnt = BCAP;
    __syncthreads();

    if (tid < cnt) {
        int2 e = binbuf[blk * BCAP + tid];
        int rl = e.x >> 8, c = e.x & 255;
        float v = __int_as_float(e.y) * tdvs[rl];
        atomicAdd(&tile[rl * 256 + c], v);
        atomicAdd(&rs[rl], v);
        atomicAdd(&cs[c], v);
    }
    __syncthreads();

    int vrows = VOCAB_P1 - row0; if (vrows > 32) vrows = 32;

    // streaming write (coalesced float4) -- dmat written exactly once
    {
        float4* out4 = (float4*)(dmat + (size_t)row0 * BATCH);
        const int lim = vrows * 64;
        #pragma unroll
        for (int k = 0; k < 8; ++k) {
            int idx = tid + k * 256;
            if (idx < lim) out4[idx] = t4[idx];
        }
    }

    if (tid < vrows) rowsum[row0 + tid] = rs[tid];
    atomicAdd(&colsum2[(blk & (CSC - 1)) * BATCH + tid], cs[tid]);
}

// K3: rel. One thread per q-entry: 1 random 4B dmat load + rowsum/colsum
// table lookups. colsum copies reduced once per block into LDS.
__global__ __launch_bounds__(256) void relv2_kernel(
    const int* __restrict__ q_rows, const int* __restrict__ q_cols,
    const float* __restrict__ q_vals, const float* __restrict__ dmat,
    const float* __restrict__ rowsum, const float* __restrict__ colsum2,
    const float* __restrict__ mu_p, float* __restrict__ rel)
{
    __shared__ float csT[BATCH];
    __shared__ float tot4[4];
    const int tid = threadIdx.x;

    float s = 0.f;
    #pragma unroll 8
    for (int k = 0; k < CSC; ++k) s += colsum2[k * BATCH + tid];
    csT[tid] = s;
    float p = s;
    for (int m = 1; m < 64; m <<= 1) p += __shfl_xor(p, m, 64);
    if ((tid & 63) == 0) tot4[tid >> 6] = p;
    __syncthreads();
    float total = tot4[0] + tot4[1] + tot4[2] + tot4[3];

    int e = blockIdx.x * 256 + tid;
    int v = q_rows[e], b = q_cols[e];
    float qv = q_vals[e];
    float mu = mu_p[0];
    float dval = dmat[(size_t)v * BATCH + b];
    float cf   = rowsum[v] / total;
    float dir  = log1pf(dval / (1.f + mu * cf)) + logf(mu / (csT[b] + mu));
    atomicAdd(&rel[b], qv * dir);
}

extern "C" void kernel_launch(void* const* d_in, const int* in_sizes, int n_in,
                              void* d_out, int out_size, void* d_ws, size_t ws_size,
                              hipStream_t stream)
{
    const int*   q_rows  = (const int*)d_in[0];
    const int*   q_cols  = (const int*)d_in[1];
    const float* q_vals  = (const float*)d_in[2];
    const int*   d_rows  = (const int*)d_in[3];
    const int*   d_cols  = (const int*)d_in[4];
    const float* d_freqs = (const float*)d_in[5];
    const float* emb     = (const float*)d_in[6];
    const float* W1      = (const float*)d_in[7];
    const float* b1      = (const float*)d_in[8];
    const float* W2      = (const float*)d_in[9];
    const float* b2      = (const float*)d_in[10];
    const float* mu      = (const float*)d_in[11];

    float* rel  = (float*)d_out;            // output 0: rel [256]
    float* dmat = rel + BATCH;              // output 1: d [100001, 256]

    char*  ws      = (char*)d_ws;
    int*   bcnt    = (int*)(ws + WS_BCNT);
    float* colsum2 = (float*)(ws + WS_CS);
    float* tdvtab  = (float*)(ws + WS_TDV);
    float* rowsum  = (float*)(ws + WS_RSUM);
    int2*  binbuf  = (int2*)(ws + WS_BIN);

    // zero bcnt + colsum copies (single small memset node, capture-legal)
    hipMemsetAsync(ws, 0, WS_TDV, stream);

    mlp_bin_kernel<<<BINBLK + 1 + MBLK, 256, 0, stream>>>(
        d_rows, d_cols, d_freqs, bcnt, binbuf,
        emb, W1, b1, W2, b2, tdvtab, rel);
    compose_kernel<<<NBKT, 256, 0, stream>>>(
        bcnt, binbuf, tdvtab, dmat, rowsum, colsum2);
    relv2_kernel<<<NNZ_Q / 256, 256, 0, stream>>>(
        q_rows, q_cols, q_vals, dmat, rowsum, colsum2, mu, rel);
}

// Round 5
// 199.756 us; speedup vs baseline: 1.1354x; 1.0509x over previous
//
#include <hip/hip_runtime.h>
#include <stdint.h>

// Problem constants (fixed by the reference).
#define VOCAB_P1 100001
#define EMB_DIM  128
#define BATCH    256
#define NNZ_Q    2048
#define NNZ_D    262144

#define NPAD 112        // hidden dim 100 padded to 7 MFMA tiles of 16
#define ROWP 136        // w1t LDS row stride in shorts (128 + 8 pad)
#define NGRP 6251       // ceil(100001 / 16) row-groups
#define ZBLK 256        // zero-role blocks
#define MBLK 1563       // mlp-role blocks: 1563*4 = 6252 waves = 1 group/wave
#define NCOPY 8         // colsum copies: 512 scatter blocks / 8 = 64-deep chains
#define OUT_F4 6400128  // out_size/4 = 25,600,512 floats / 4

typedef __attribute__((ext_vector_type(8))) short  short8;
typedef __attribute__((ext_vector_type(4))) float  float4v;

__device__ __forceinline__ unsigned short f2bf(float f) {
    union { float f; unsigned u; } v; v.f = f;
    unsigned u = v.u;
    u += 0x7fffu + ((u >> 16) & 1u);     // RNE float -> bf16
    return (unsigned short)(u >> 16);
}

__device__ __forceinline__ short8 cvt8(float4 a, float4 b) {
    short8 r;
    r[0] = (short)f2bf(a.x); r[1] = (short)f2bf(a.y);
    r[2] = (short)f2bf(a.z); r[3] = (short)f2bf(a.w);
    r[4] = (short)f2bf(b.x); r[5] = (short)f2bf(b.y);
    r[6] = (short)f2bf(b.z); r[7] = (short)f2bf(b.w);
    return r;
}

// Block-role fused kernel (R0-proven, fastest measured structure):
//   blocks [0, ZBLK): zero d_out (rel + dmat) and the colsum copies.
//   blocks [ZBLK, ZBLK+MBLK): per-unique-row MLP tdv table, exactly ONE
//   16-row group per wave (balanced; no 2-group tail).
// The 102.4MB dense zero-write runs CONCURRENT with the MLP role -- keeping
// it off the serial critical path (R1/R2/R4 alternatives all regressed).
__global__ __launch_bounds__(256) void zero_mlp_kernel(
    float* __restrict__ d_out_f, float* __restrict__ colsum2,
    const float* __restrict__ emb, const float* __restrict__ W1,
    const float* __restrict__ b1, const float* __restrict__ W2,
    const float* __restrict__ b2, float* __restrict__ tdvtab)
{
    const int tid = threadIdx.x;

    if (blockIdx.x < ZBLK) {
        const float4 z = {0.f, 0.f, 0.f, 0.f};
        float4* dst = (float4*)d_out_f;
        int i0 = blockIdx.x * 256 + tid;
        int i = i0;
        for (; i + ZBLK * 256 < OUT_F4; i += 2 * ZBLK * 256) {
            dst[i] = z;
            dst[i + ZBLK * 256] = z;
        }
        if (i < OUT_F4) dst[i] = z;
        if (i0 < NCOPY * BATCH / 4) ((float4*)colsum2)[i0] = z;
        return;
    }

    __shared__ __align__(16) short w1t[NPAD * ROWP];   // 30.5 KB
    __shared__ float b1s[NPAD];
    __shared__ float w2s[NPAD];

    int* w1i = (int*)w1t;
    for (int i = tid; i < NPAD * ROWP / 2; i += 256) w1i[i] = 0;
    __syncthreads();
    for (int f = tid; f < EMB_DIM * 100; f += 256) {
        int k = f / 100, j = f - k * 100;
        w1t[j * ROWP + k] = (short)f2bf(W1[f]);
    }
    if (tid < NPAD) {
        b1s[tid] = (tid < 100) ? b1[tid] : 0.f;
        w2s[tid] = (tid < 100) ? W2[tid] : 0.f;
    }
    __syncthreads();

    const int lane = tid & 63;
    const int w    = tid >> 6;
    const int col  = lane & 15;
    const int quad = lane >> 4;
    const float b2v = b2[0];

    const int grp = (blockIdx.x - ZBLK) * 4 + w;   // one group per wave
    if (grp >= NGRP) return;

    int r  = grp * 16 + col;
    int rr = (r <= VOCAB_P1 - 1) ? r : (VOCAB_P1 - 1);
    const float* rp = emb + (size_t)rr * EMB_DIM + quad * 8;
    // A layout: A[m=lane&15][k=quad*8+j]  (m89/m91-verified)
    float4 u0 = *(const float4*)(rp);
    float4 u1 = *(const float4*)(rp + 4);
    float4 u2 = *(const float4*)(rp + 32);
    float4 u3 = *(const float4*)(rp + 36);
    float4 u4 = *(const float4*)(rp + 64);
    float4 u5 = *(const float4*)(rp + 68);
    float4 u6 = *(const float4*)(rp + 96);
    float4 u7 = *(const float4*)(rp + 100);
    short8 a0 = cvt8(u0, u1), a1 = cvt8(u2, u3);
    short8 a2 = cvt8(u4, u5), a3 = cvt8(u6, u7);

    float s0 = 0.f, s1 = 0.f, s2 = 0.f, s3 = 0.f;
    for (int jt = 0; jt < 7; ++jt) {
        const short* bp = &w1t[(jt * 16 + col) * ROWP + quad * 8];
        short8 bv0 = *(const short8*)(bp);
        short8 bv1 = *(const short8*)(bp + 32);
        short8 bv2 = *(const short8*)(bp + 64);
        short8 bv3 = *(const short8*)(bp + 96);

        float4v acc = {0.f, 0.f, 0.f, 0.f};
        acc = __builtin_amdgcn_mfma_f32_16x16x32_bf16(a0, bv0, acc, 0, 0, 0);
        acc = __builtin_amdgcn_mfma_f32_16x16x32_bf16(a1, bv1, acc, 0, 0, 0);
        acc = __builtin_amdgcn_mfma_f32_16x16x32_bf16(a2, bv2, acc, 0, 0, 0);
        acc = __builtin_amdgcn_mfma_f32_16x16x32_bf16(a3, bv3, acc, 0, 0, 0);

        // D layout: row = quad*4 + reg, col(j) = lane&15
        float b1v = b1s[jt * 16 + col];
        float w2v = w2s[jt * 16 + col];
        float h;
        h = acc[0] + b1v; h = h > 0.f ? h : 0.f; s0 += h * w2v;
        h = acc[1] + b1v; h = h > 0.f ? h : 0.f; s1 += h * w2v;
        h = acc[2] + b1v; h = h > 0.f ? h : 0.f; s2 += h * w2v;
        h = acc[3] + b1v; h = h > 0.f ? h : 0.f; s3 += h * w2v;
    }
    for (int m = 1; m < 16; m <<= 1) {
        s0 += __shfl_xor(s0, m, 64);
        s1 += __shfl_xor(s1, m, 64);
        s2 += __shfl_xor(s2, m, 64);
        s3 += __shfl_xor(s3, m, 64);
    }
    if (col < 4) {
        float sv = (col == 0) ? s0 : (col == 1) ? s1 : (col == 2) ? s2 : s3;
        int row = grp * 16 + quad * 4 + col;
        if (row < VOCAB_P1) {
            float tdv = sv + b2v;
            tdvtab[row] = tdv > 0.f ? tdv : 0.f;
        }
    }
}

// Scatter (R0-measured best): 512 blocks x 2 entries/thread (8 waves/CU).
// LDS colsum per block; flushed to NCOPY=8 copies by block index (64-deep
// per-address atomic chains instead of 256-deep at NCOPY=2).
__global__ __launch_bounds__(256) void scatter_kernel(
    const int* __restrict__ d_rows, const int* __restrict__ d_cols,
    const float* __restrict__ d_freqs, const float* __restrict__ tdvtab,
    float* __restrict__ dmat, float* __restrict__ colsum2)
{
    __shared__ float cs[BATCH];
    const int tid = threadIdx.x;
    cs[tid] = 0.f;
    __syncthreads();

    int g = blockIdx.x * 256 + tid;              // int2 index, 131072 total
    int2   r2 = ((const int2*)d_rows)[g];
    int2   c2 = ((const int2*)d_cols)[g];
    float2 f2 = ((const float2*)d_freqs)[g];

    float ft0 = tdvtab[r2.x] * f2.x;
    float ft1 = tdvtab[r2.y] * f2.y;

    atomicAdd(&dmat[(size_t)r2.x * BATCH + c2.x], ft0);
    atomicAdd(&dmat[(size_t)r2.y * BATCH + c2.y], ft1);
    atomicAdd(&cs[c2.x], ft0);
    atomicAdd(&cs[c2.y], ft1);

    __syncthreads();
    atomicAdd(&colsum2[(blockIdx.x & (NCOPY - 1)) * BATCH + tid], cs[tid]);
}

// One WAVE per q-entry: rowsum[v] = sum of dmat row v (1 float4/lane),
// total = sum over colsum copies, both shuffle-reduced in-wave.
__global__ __launch_bounds__(256) void rel_kernel(
    const int* __restrict__ q_rows, const int* __restrict__ q_cols,
    const float* __restrict__ q_vals, const float* __restrict__ dmat,
    const float* __restrict__ colsum2, const float* __restrict__ mu_p,
    float* __restrict__ rel)
{
    const int tid  = threadIdx.x;
    const int lane = tid & 63;
    const int e    = blockIdx.x * 4 + (tid >> 6);   // 512 blocks x 4 waves

    int v = q_rows[e], b = q_cols[e];
    float qv = q_vals[e];
    float mu = mu_p[0];

    float tot_p = 0.f;
    #pragma unroll
    for (int k = 0; k < NCOPY; ++k) {
        float4 cv = *(const float4*)(colsum2 + k * BATCH + lane * 4);
        tot_p += cv.x + cv.y + cv.z + cv.w;
    }
    float4 rv = *(const float4*)(dmat + (size_t)v * BATCH + lane * 4);
    float row_p = rv.x + rv.y + rv.z + rv.w;
    for (int m = 1; m < 64; m <<= 1) {
        tot_p += __shfl_xor(tot_p, m, 64);
        row_p += __shfl_xor(row_p, m, 64);
    }

    if (lane == 0) {
        float csb = 0.f;
        #pragma unroll
        for (int k = 0; k < NCOPY; ++k) csb += colsum2[k * BATCH + b];
        float dval = dmat[(size_t)v * BATCH + b];
        float cf   = row_p / tot_p;
        float dir  = log1pf(dval / (1.f + mu * cf)) + logf(mu / (csb + mu));
        atomicAdd(&rel[b], qv * dir);
    }
}

extern "C" void kernel_launch(void* const* d_in, const int* in_sizes, int n_in,
                              void* d_out, int out_size, void* d_ws, size_t ws_size,
                              hipStream_t stream)
{
    const int*   q_rows  = (const int*)d_in[0];
    const int*   q_cols  = (const int*)d_in[1];
    const float* q_vals  = (const float*)d_in[2];
    const int*   d_rows  = (const int*)d_in[3];
    const int*   d_cols  = (const int*)d_in[4];
    const float* d_freqs = (const float*)d_in[5];
    const float* emb     = (const float*)d_in[6];
    const float* W1      = (const float*)d_in[7];
    const float* b1      = (const float*)d_in[8];
    const float* W2      = (const float*)d_in[9];
    const float* b2      = (const float*)d_in[10];
    const float* mu      = (const float*)d_in[11];

    float* rel  = (float*)d_out;            // output 0: rel [256]
    float* dmat = rel + BATCH;              // output 1: d [100001, 256]

    float* colsum2 = (float*)d_ws;          // [NCOPY][256]
    float* tdvtab  = colsum2 + NCOPY * BATCH;  // [100001]

    zero_mlp_kernel<<<ZBLK + MBLK, 256, 0, stream>>>(
        (float*)d_out, colsum2, emb, W1, b1, W2, b2, tdvtab);
    scatter_kernel<<<NNZ_D / 512, 256, 0, stream>>>(
        d_rows, d_cols, d_freqs, tdvtab, dmat, colsum2);
    rel_kernel<<<NNZ_Q / 4, 256, 0, stream>>>(
        q_rows, q_cols, q_vals, dmat, colsum2, mu, rel);
}